// Round 4
// baseline (338.557 us; speedup 1.0000x reference)
//
#include <hip/hip_runtime.h>

typedef _Float16 half8   __attribute__((ext_vector_type(8)));
typedef _Float16 half4_t __attribute__((ext_vector_type(4)));
typedef float    float4_t __attribute__((ext_vector_type(4)));

#define B_   8
#define N_   4096
#define C_   256
#define F_   64
#define NROW (B_ * N_)                 // 32768 rows total
#define OPHALF ((size_t)NROW * C_)     // elements per O-half (8.4M f16 = 16 MiB)

#if defined(__has_builtin) && __has_builtin(__builtin_amdgcn_exp2f)
#define EXP2(x) __builtin_amdgcn_exp2f(x)
#else
#define EXP2(x) exp2f(x)
#endif
#define LOG2E 1.44269504f

static __device__ __forceinline__ float4_t mfma16(half8 a, half8 b, float4_t c) {
  return __builtin_amdgcn_mfma_f32_16x16x32_f16(a, b, c, 0, 0, 0);
}

// DPP cross-lane within 16-lane rows: row_ror:N = 0x120|N.
template <int CTRL>
static __device__ __forceinline__ float dpp_f(float x) {
  return __int_as_float(__builtin_amdgcn_update_dpp(
      __float_as_int(x), __float_as_int(x), CTRL, 0xF, 0xF, false));
}
static __device__ __forceinline__ float row_max16(float v) {
  v = fmaxf(v, dpp_f<0x128>(v));
  v = fmaxf(v, dpp_f<0x124>(v));
  v = fmaxf(v, dpp_f<0x122>(v));
  v = fmaxf(v, dpp_f<0x121>(v));
  return v;
}
static __device__ __forceinline__ float row_sum16(float v) {
  v += dpp_f<0x128>(v);
  v += dpp_f<0x124>(v);
  v += dpp_f<0x122>(v);
  v += dpp_f<0x121>(v);
  return v;
}

// Async global->LDS K staging with PRE-SWIZZLED per-lane source.
// LDS dest is linear (wave-uniform base + lane*16B, the HW constraint);
// the XOR swizzle lives in the per-lane SOURCE column. Swizzle granule
// (8 halves = 16B) == load width, so LDS[row][blk] = G[row][blk ^ (row&7)],
// identical to the old ds_write layout; the swizzled read side is unchanged.
// Each wave stages rows [16w, 16w+16) of the 64x64 tile in 2 instructions.
static __device__ __forceinline__ void stage_k(const _Float16* gsrc,  // + j0*64
                                               _Float16* kd,          // tile base
                                               int wave, int lane) {
  const int srow = lane >> 3;              // 0..7
  const int sblk = (lane & 7) ^ srow;      // swizzled source 16B-block
  const _Float16* s = gsrc + (size_t)(wave * 16 + srow) * 64 + (sblk << 3);
  _Float16* d = kd + (wave * 16) * 64;     // wave-uniform
  __builtin_amdgcn_global_load_lds(
      (const __attribute__((address_space(1))) unsigned int*)s,
      (__attribute__((address_space(3))) unsigned int*)d, 16, 0, 0);
  s += 8 * 64;
  d += 8 * 64;
  __builtin_amdgcn_global_load_lds(
      (const __attribute__((address_space(1))) unsigned int*)s,
      (__attribute__((address_space(3))) unsigned int*)d, 16, 0, 0);
}

// ---------------- prep: WhvT[d][c] = sum_e Wh[c][e]*Wv[e][d], f16 ----------------
__global__ __launch_bounds__(256) void prep_whvt(const float* __restrict__ Wh,
                                                 const float* __restrict__ Wv,
                                                 _Float16* __restrict__ whvt) {
  int d = blockIdx.x;
  int c = threadIdx.x;
  const float4_t* whr = (const float4_t*)(Wh + (size_t)c * 256);
  float acc = 0.f;
#pragma unroll 8
  for (int e4 = 0; e4 < 64; ++e4) {
    float4_t w4 = whr[e4];
    acc += w4[0] * Wv[(e4 * 4 + 0) * 256 + d];
    acc += w4[1] * Wv[(e4 * 4 + 1) * 256 + d];
    acc += w4[2] * Wv[(e4 * 4 + 2) * 256 + d];
    acc += w4[3] * Wv[(e4 * 4 + 3) * 256 + d];
  }
  whvt[d * 256 + c] = (_Float16)acc;
}

// ---- prep: wfgt[n][c] = (n<64 ? Wf[c][n]*log2e : Wg[c][n-64]), f16 --------------
__global__ __launch_bounds__(256) void prep_wfgt(const float* __restrict__ Wf,
                                                 const float* __restrict__ Wg,
                                                 _Float16* __restrict__ wfgt) {
  int n = blockIdx.x;
  int c = threadIdx.x;
  float v = (n < 64) ? Wf[c * 64 + n] * LOG2E : Wg[c * 64 + (n - 64)];
  wfgt[n * 256 + c] = (_Float16)v;
}

// ---------------- prep: xT[b][c][n] = (f16)x[b][n][c] ----------------------------
__global__ __launch_bounds__(256) void transpose_x(const float* __restrict__ x,
                                                   _Float16* __restrict__ xT) {
  __shared__ float tile[32][33];
  int b  = blockIdx.x >> 7;
  int n0 = (blockIdx.x & 127) << 5;
  int c0 = blockIdx.y << 5;
  int tid = threadIdx.x;
  int r  = tid >> 3;
  int cc = (tid & 7) << 2;
  const float* src = x + ((size_t)(b * N_ + n0 + r)) * C_ + c0 + cc;
  float4_t v = *(const float4_t*)src;
  tile[r][cc + 0] = v[0]; tile[r][cc + 1] = v[1];
  tile[r][cc + 2] = v[2]; tile[r][cc + 3] = v[3];
  __syncthreads();
  half4_t o;
  o[0] = (_Float16)tile[cc + 0][r];
  o[1] = (_Float16)tile[cc + 1][r];
  o[2] = (_Float16)tile[cc + 2][r];
  o[3] = (_Float16)tile[cc + 3][r];
  _Float16* dst = xT + ((size_t)(b * C_ + c0 + r)) * N_ + n0 + cc;
  *(half4_t*)dst = o;
}

// ---------------- f,g GEMM: [32768x256] @ wfgt^T -> f16 [32768x64] x2 ------------
__global__ __launch_bounds__(256) void fg_kernel(const float* __restrict__ x,
                                                 const _Float16* __restrict__ wfgt,
                                                 _Float16* __restrict__ f,
                                                 _Float16* __restrict__ g) {
  int tid  = threadIdx.x;
  int wave = tid >> 6, lane = tid & 63;
  int n16  = lane & 15, quad = lane >> 4;
  int row  = blockIdx.x * 64 + wave * 16 + n16;
  float4_t acc[8];
#pragma unroll
  for (int t = 0; t < 8; t++) acc[t] = (float4_t){0.f, 0.f, 0.f, 0.f};
  for (int k0 = 0; k0 < 256; k0 += 32) {
    const float* xp = x + (size_t)row * C_ + k0 + quad * 8;
    float4_t x0 = *(const float4_t*)xp;
    float4_t x1 = *(const float4_t*)(xp + 4);
    half8 af;
#pragma unroll
    for (int j = 0; j < 4; j++) { af[j] = (_Float16)x0[j]; af[4 + j] = (_Float16)x1[j]; }
#pragma unroll
    for (int t = 0; t < 8; t++) {
      half8 bf = *(const half8*)(wfgt + (size_t)(t * 16 + n16) * 256 + k0 + quad * 8);
      acc[t] = mfma16(af, bf, acc[t]);
    }
  }
  int orow = blockIdx.x * 64 + wave * 16 + quad * 4;
#pragma unroll
  for (int t = 0; t < 8; t++) {
#pragma unroll
    for (int r = 0; r < 4; r++) {
      _Float16 v = (_Float16)acc[t][r];
      int col = t * 16 + n16;
      if (t < 4) f[(size_t)(orow + r) * 64 + col] = v;
      else       g[(size_t)(orow + r) * 64 + col - 64] = v;
    }
  }
}

// ---------------- flash attention, 2-way KV split ---------------------------------
// grid (B, N/64, 2). Register budget is the occupancy lever: Round-3 counters
// showed 2 blocks/CU (20.5% occ) at ~190 unified regs. Trims here: K staging
// via global_load_lds (no kp regs, no ds_writes), V s=1 loads moved below the
// softmax pressure peak, and __launch_bounds__(256,3) to target <=170 regs ->
// 3 blocks/CU. ((256,4)=128 regs spilled catastrophically in Round 2.)
__global__ __launch_bounds__(256, 3) void flash_kernel(const _Float16* __restrict__ f,
                                                       const _Float16* __restrict__ g,
                                                       const _Float16* __restrict__ xT,
                                                       _Float16* __restrict__ op,
                                                       float* __restrict__ ml) {
  __shared__ _Float16 ktb2[2][64 * 64];   // K tile, swizzled
  __shared__ _Float16 ptb2[2][64 * 64];   // P tile, swizzled
  __shared__ float alpha_lds[2][64];
  __shared__ int   aflag[2][4];           // per-wave "max moved" flags

  const int b   = blockIdx.x;
  const int i0  = blockIdx.y * 64;
  const int jh  = blockIdx.z;
  const int jbase = jh << 11;             // 0 or 2048
  const int tid = threadIdx.x;
  const int wave = tid >> 6, lane = tid & 63;
  const int n16 = lane & 15, quad = lane >> 4;
  const int nlo = n16 & 7, nhi = n16 >> 3;

  // Q fragments (A-layout: m=n16, k=quad*8+j); Q pre-scaled by log2e via prep
  half8 qf[2];
  {
    const _Float16* qp = f + (size_t)(b * N_ + i0 + wave * 16 + n16) * 64 + quad * 8;
    qf[0] = *(const half8*)qp;
    qf[1] = *(const half8*)(qp + 32);
  }

  float4_t o_acc[16];   // [ti*4+ct]: rows ti*16+4q+r, cols 64w+16ct+n16
#pragma unroll
  for (int t = 0; t < 16; t++) o_acc[t] = (float4_t){0.f, 0.f, 0.f, 0.f};
  float m_i[4] = {-1e30f, -1e30f, -1e30f, -1e30f};   // log2-domain running max
  float l_i[4] = {0.f, 0.f, 0.f, 0.f};

  const _Float16* gbase = g + (size_t)(b * N_) * 64;
  const _Float16* xbase = xT + ((size_t)b * C_ + 64 * wave) * (size_t)N_;

  // stage K tile for the first j-tile of this half (async, drained by barrier)
  stage_k(gbase + (size_t)jbase * 64, ktb2[0], wave, lane);
  __syncthreads();

  for (int k = 0; k < 32; ++k) {
    const int j0  = jbase + (k << 6);
    const int buf = k & 1;
    const int j0n = jbase + (((k + 1) & 31) << 6);

    // async-stage next K tile into the other buffer (completes by the barrier)
    stage_k(gbase + (size_t)j0n * 64, ktb2[buf ^ 1], wave, lane);

    // V fragments, s=0 half, straight from global (L2/L3)
    half8 vfr[8];
#pragma unroll
    for (int ct = 0; ct < 4; ct++)
      vfr[ct] = *(const half8*)(xbase + (size_t)(16 * ct + n16) * N_ +
                                j0 + 8 * quad);

    // S = Q K^T (already log2-scaled)
    float4_t s_acc[4];
#pragma unroll
    for (int t = 0; t < 4; t++) s_acc[t] = (float4_t){0.f, 0.f, 0.f, 0.f};
    {
      const _Float16* ktb = ktb2[buf];
      __builtin_amdgcn_s_setprio(1);
#pragma unroll
      for (int s = 0; s < 2; s++)
#pragma unroll
        for (int t = 0; t < 4; t++) {
          half8 bf = *(const half8*)(ktb + (16 * t + n16) * 64 +
                                     (((4 * s + quad) ^ nlo) << 3));
          s_acc[t] = mfma16(qf[s], bf, s_acc[t]);
        }
      __builtin_amdgcn_s_setprio(0);
    }

    // online softmax (base-2); write P (swizzled) + alpha + flag to LDS
    float alpha_r[4];
#pragma unroll
    for (int r = 0; r < 4; r++) {
      float v = fmaxf(fmaxf(s_acc[0][r], s_acc[1][r]),
                      fmaxf(s_acc[2][r], s_acc[3][r]));
      v = row_max16(v);
      float mn = fmaxf(m_i[r], v);
      alpha_r[r] = EXP2(m_i[r] - mn);
      m_i[r] = mn;
    }
    {
      float am = fminf(fminf(alpha_r[0], alpha_r[1]),
                       fminf(alpha_r[2], alpha_r[3]));
      unsigned long long bm = __ballot(am < 1.0f);
      if (lane == 0) aflag[buf][wave] = (bm != 0ULL) ? 1 : 0;
    }
    _Float16* pb = ptb2[buf];
#pragma unroll
    for (int r = 0; r < 4; r++) {
      float s0 = EXP2(s_acc[0][r] - m_i[r]);
      float s1 = EXP2(s_acc[1][r] - m_i[r]);
      float s2 = EXP2(s_acc[2][r] - m_i[r]);
      float s3 = EXP2(s_acc[3][r] - m_i[r]);
      float v = row_sum16(s0 + s1 + s2 + s3);
      l_i[r] = l_i[r] * alpha_r[r] + v;
      const int row = wave * 16 + 4 * quad + r;
      const int rb  = row & 7;
      _Float16* pr = pb + row * 64 + nlo;
      pr[((nhi    ) ^ rb) << 3] = (_Float16)s0;
      pr[((nhi + 2) ^ rb) << 3] = (_Float16)s1;
      pr[((nhi + 4) ^ rb) << 3] = (_Float16)s2;
      pr[((nhi + 6) ^ rb) << 3] = (_Float16)s3;
    }
    if (n16 == 0) {
#pragma unroll
      for (int r = 0; r < 4; r++)
        alpha_lds[buf][wave * 16 + 4 * quad + r] = alpha_r[r];
    }

    // V fragments, s=1 half, loaded BELOW the softmax register-pressure peak;
    // sched_barrier stops the compiler hoisting them back up. They complete
    // during the barrier's vmcnt drain.
    __builtin_amdgcn_sched_barrier(0);
#pragma unroll
    for (int ct = 0; ct < 4; ct++)
      vfr[4 + ct] = *(const half8*)(xbase + (size_t)(16 * ct + n16) * N_ +
                                    j0 + 32 + 8 * quad);
    __syncthreads();

    // rescale O, skipping row-tiles whose max didn't move (alpha==1 exactly)
#pragma unroll
    for (int ti = 0; ti < 4; ti++) {
      if (aflag[buf][ti]) {
#pragma unroll
        for (int r = 0; r < 4; r++) {
          float al = alpha_lds[buf][ti * 16 + 4 * quad + r];
#pragma unroll
          for (int ct = 0; ct < 4; ct++) o_acc[ti * 4 + ct][r] *= al;
        }
      }
    }

    // O += P V
    __builtin_amdgcn_s_setprio(1);
#pragma unroll
    for (int s = 0; s < 2; s++)
#pragma unroll
      for (int ti = 0; ti < 4; ti++) {
        half8 af = *(const half8*)(pb + (16 * ti + n16) * 64 +
                                   (((4 * s + quad) ^ nlo) << 3));
#pragma unroll
        for (int ct = 0; ct < 4; ct++)
          o_acc[ti * 4 + ct] = mfma16(af, vfr[s * 4 + ct], o_acc[ti * 4 + ct]);
      }
    __builtin_amdgcn_s_setprio(0);
  }

  // emit unnormalized O-half + per-row (m,l); merge happens in out_kernel
  _Float16* ob = op + (size_t)jh * OPHALF;
#pragma unroll
  for (int ti = 0; ti < 4; ti++)
#pragma unroll
    for (int r = 0; r < 4; r++) {
      size_t orow = (size_t)(b * N_ + i0 + ti * 16 + 4 * quad + r) * C_;
#pragma unroll
      for (int ct = 0; ct < 4; ct++)
        ob[orow + 64 * wave + 16 * ct + n16] = (_Float16)o_acc[ti * 4 + ct][r];
    }
  if (n16 == 0) {
#pragma unroll
    for (int r = 0; r < 4; r++) {
      int rowg = b * N_ + i0 + wave * 16 + 4 * quad + r;
      ml[(size_t)(jh * 2 + 0) * NROW + rowg] = m_i[r];
      ml[(size_t)(jh * 2 + 1) * NROW + rowg] = l_i[r];
    }
  }
}

// ------- epilogue GEMM + softmax merge: out = gamma * (merge(O1,O2) @ Whv) + x ---
__global__ __launch_bounds__(256) void out_kernel(const _Float16* __restrict__ op,
                                                  const float* __restrict__ ml,
                                                  const _Float16* __restrict__ whvt,
                                                  const float* __restrict__ x,
                                                  const float* __restrict__ gamma,
                                                  float* __restrict__ out) {
  int tid  = threadIdx.x;
  int wave = tid >> 6, lane = tid & 63;
  int n16  = lane & 15, quad = lane >> 4;
  int row  = blockIdx.x * 64 + wave * 16 + n16;
  // per-row merge weights (computed once; f32 for accuracy)
  float m1 = ml[row],            l1 = ml[NROW + row];
  float m2 = ml[2 * NROW + row], l2 = ml[3 * NROW + row];
  float ms = fmaxf(m1, m2);
  float u1 = EXP2(m1 - ms), u2 = EXP2(m2 - ms);
  float inv = 1.f / (l1 * u1 + l2 * u2);
  float c1 = u1 * inv, c2 = u2 * inv;
  const _Float16* o1 = op + (size_t)row * C_;
  const _Float16* o2 = o1 + OPHALF;
  float4_t acc[16];
#pragma unroll
  for (int t = 0; t < 16; t++) acc[t] = (float4_t){0.f, 0.f, 0.f, 0.f};
  for (int k0 = 0; k0 < 256; k0 += 32) {
    half8 a1 = *(const half8*)(o1 + k0 + quad * 8);
    half8 a2 = *(const half8*)(o2 + k0 + quad * 8);
    half8 af;
#pragma unroll
    for (int j = 0; j < 8; j++)
      af[j] = (_Float16)((float)a1[j] * c1 + (float)a2[j] * c2);
#pragma unroll
    for (int t = 0; t < 16; t++) {
      half8 bf = *(const half8*)(whvt + (size_t)(t * 16 + n16) * 256 + k0 + quad * 8);
      acc[t] = mfma16(af, bf, acc[t]);
    }
  }
  float gm = gamma[0];
  int orow = blockIdx.x * 64 + wave * 16 + quad * 4;
#pragma unroll
  for (int t = 0; t < 16; t++) {
#pragma unroll
    for (int r = 0; r < 4; r++) {
      size_t idx = (size_t)(orow + r) * C_ + t * 16 + n16;
      out[idx] = gm * acc[t][r] + x[idx];
    }
  }
}

extern "C" void kernel_launch(void* const* d_in, const int* in_sizes, int n_in,
                              void* d_out, int out_size, void* d_ws, size_t ws_size,
                              hipStream_t stream) {
  const float* x     = (const float*)d_in[0];
  const float* Wf    = (const float*)d_in[1];
  const float* Wg    = (const float*)d_in[2];
  const float* Wh    = (const float*)d_in[3];
  const float* Wv    = (const float*)d_in[4];
  const float* gamma = (const float*)d_in[5];
  float* out = (float*)d_out;

  char* w = (char*)d_ws;
  _Float16* whvt = (_Float16*)(w);                                  // 128 KiB
  _Float16* wfgt = (_Float16*)(w + 131072);                         //  64 KiB
  _Float16* fb   = (_Float16*)(w + 196608);                         //   4 MiB
  _Float16* gb   = (_Float16*)(w + 196608 + 4194304);               //   4 MiB
  _Float16* xT   = (_Float16*)(w + 196608 + 2 * 4194304);           //  16 MiB
  _Float16* op   = (_Float16*)(w + 196608 + 2 * 4194304 + 16777216);//  32 MiB (2 halves)
  float*    ml   = (float*)   (w + 196608 + 2 * 4194304 + 16777216 + 33554432); // 512 KiB

  hipLaunchKernelGGL(prep_whvt,  dim3(256),     dim3(256), 0, stream, Wh, Wv, whvt);
  hipLaunchKernelGGL(prep_wfgt,  dim3(128),     dim3(256), 0, stream, Wf, Wg, wfgt);
  hipLaunchKernelGGL(transpose_x,dim3(1024, 8), dim3(256), 0, stream, x, xT);
  hipLaunchKernelGGL(fg_kernel,  dim3(512),     dim3(256), 0, stream, x, wfgt, fb, gb);
  hipLaunchKernelGGL(flash_kernel, dim3(8, 64, 2), dim3(256), 0, stream, fb, gb, xT, op, ml);
  hipLaunchKernelGGL(out_kernel, dim3(512),     dim3(256), 0, stream, op, ml, whvt, x, gamma, out);
}

// Round 5
// 301.623 us; speedup vs baseline: 1.1225x; 1.1225x over previous
//
#include <hip/hip_runtime.h>

typedef _Float16 half8   __attribute__((ext_vector_type(8)));
typedef _Float16 half4_t __attribute__((ext_vector_type(4)));
typedef float    float4_t __attribute__((ext_vector_type(4)));

#define B_   8
#define N_   4096
#define C_   256
#define F_   64

#if defined(__has_builtin) && __has_builtin(__builtin_amdgcn_exp2f)
#define EXP2(x) __builtin_amdgcn_exp2f(x)
#else
#define EXP2(x) exp2f(x)
#endif
#define LOG2E 1.44269504f

static __device__ __forceinline__ float4_t mfma16(half8 a, half8 b, float4_t c) {
  return __builtin_amdgcn_mfma_f32_16x16x32_f16(a, b, c, 0, 0, 0);
}

// DPP cross-lane within 16-lane rows: row_ror:N = 0x120|N.
template <int CTRL>
static __device__ __forceinline__ float dpp_f(float x) {
  return __int_as_float(__builtin_amdgcn_update_dpp(
      __float_as_int(x), __float_as_int(x), CTRL, 0xF, 0xF, false));
}
static __device__ __forceinline__ float row_max16(float v) {
  v = fmaxf(v, dpp_f<0x128>(v));
  v = fmaxf(v, dpp_f<0x124>(v));
  v = fmaxf(v, dpp_f<0x122>(v));
  v = fmaxf(v, dpp_f<0x121>(v));
  return v;
}
static __device__ __forceinline__ float row_sum16(float v) {
  v += dpp_f<0x128>(v);
  v += dpp_f<0x124>(v);
  v += dpp_f<0x122>(v);
  v += dpp_f<0x121>(v);
  return v;
}

// ---------------- prep: WhvT[d][c] = sum_e Wh[c][e]*Wv[e][d], f16 ----------------
__global__ __launch_bounds__(256) void prep_whvt(const float* __restrict__ Wh,
                                                 const float* __restrict__ Wv,
                                                 _Float16* __restrict__ whvt) {
  int d = blockIdx.x;
  int c = threadIdx.x;
  const float4_t* whr = (const float4_t*)(Wh + (size_t)c * 256);
  float acc = 0.f;
#pragma unroll 8
  for (int e4 = 0; e4 < 64; ++e4) {
    float4_t w4 = whr[e4];
    acc += w4[0] * Wv[(e4 * 4 + 0) * 256 + d];
    acc += w4[1] * Wv[(e4 * 4 + 1) * 256 + d];
    acc += w4[2] * Wv[(e4 * 4 + 2) * 256 + d];
    acc += w4[3] * Wv[(e4 * 4 + 3) * 256 + d];
  }
  whvt[d * 256 + c] = (_Float16)acc;
}

// ---- prep: wfgt[n][c] = (n<64 ? Wf[c][n]*log2e : Wg[c][n-64]), f16 --------------
__global__ __launch_bounds__(256) void prep_wfgt(const float* __restrict__ Wf,
                                                 const float* __restrict__ Wg,
                                                 _Float16* __restrict__ wfgt) {
  int n = blockIdx.x;
  int c = threadIdx.x;
  float v = (n < 64) ? Wf[c * 64 + n] * LOG2E : Wg[c * 64 + (n - 64)];
  wfgt[n * 256 + c] = (_Float16)v;
}

// ---------------- prep: xT[b][c][n] = (f16)x[b][n][c] ----------------------------
__global__ __launch_bounds__(256) void transpose_x(const float* __restrict__ x,
                                                   _Float16* __restrict__ xT) {
  __shared__ float tile[32][33];
  int b  = blockIdx.x >> 7;
  int n0 = (blockIdx.x & 127) << 5;
  int c0 = blockIdx.y << 5;
  int tid = threadIdx.x;
  int r  = tid >> 3;
  int cc = (tid & 7) << 2;
  const float* src = x + ((size_t)(b * N_ + n0 + r)) * C_ + c0 + cc;
  float4_t v = *(const float4_t*)src;
  tile[r][cc + 0] = v[0]; tile[r][cc + 1] = v[1];
  tile[r][cc + 2] = v[2]; tile[r][cc + 3] = v[3];
  __syncthreads();
  half4_t o;
  o[0] = (_Float16)tile[cc + 0][r];
  o[1] = (_Float16)tile[cc + 1][r];
  o[2] = (_Float16)tile[cc + 2][r];
  o[3] = (_Float16)tile[cc + 3][r];
  _Float16* dst = xT + ((size_t)(b * C_ + c0 + r)) * N_ + n0 + cc;
  *(half4_t*)dst = o;
}

// ---------------- f,g GEMM: [32768x256] @ wfgt^T -> f16 [32768x64] x2 ------------
__global__ __launch_bounds__(256) void fg_kernel(const float* __restrict__ x,
                                                 const _Float16* __restrict__ wfgt,
                                                 _Float16* __restrict__ f,
                                                 _Float16* __restrict__ g) {
  int tid  = threadIdx.x;
  int wave = tid >> 6, lane = tid & 63;
  int n16  = lane & 15, quad = lane >> 4;
  int row  = blockIdx.x * 64 + wave * 16 + n16;
  float4_t acc[8];
#pragma unroll
  for (int t = 0; t < 8; t++) acc[t] = (float4_t){0.f, 0.f, 0.f, 0.f};
  for (int k0 = 0; k0 < 256; k0 += 32) {
    const float* xp = x + (size_t)row * C_ + k0 + quad * 8;
    float4_t x0 = *(const float4_t*)xp;
    float4_t x1 = *(const float4_t*)(xp + 4);
    half8 af;
#pragma unroll
    for (int j = 0; j < 4; j++) { af[j] = (_Float16)x0[j]; af[4 + j] = (_Float16)x1[j]; }
#pragma unroll
    for (int t = 0; t < 8; t++) {
      half8 bf = *(const half8*)(wfgt + (size_t)(t * 16 + n16) * 256 + k0 + quad * 8);
      acc[t] = mfma16(af, bf, acc[t]);
    }
  }
  int orow = blockIdx.x * 64 + wave * 16 + quad * 4;
#pragma unroll
  for (int t = 0; t < 8; t++) {
#pragma unroll
    for (int r = 0; r < 4; r++) {
      _Float16 v = (_Float16)acc[t][r];
      int col = t * 16 + n16;
      if (t < 4) f[(size_t)(orow + r) * 64 + col] = v;
      else       g[(size_t)(orow + r) * 64 + col - 64] = v;
    }
  }
}

// ---------------- flash attention (C-split), KVBLK=128 ---------------------------
// R1 structure (no KV split, register-prefetch K staging, all V loads at iter
// top, (256,2) so ~214 live regs fit the 256/wave budget at 2 blocks/CU) BUT
// two 64-wide j-tiles are processed per barrier with a COMMON max: exact
// online softmax, half the barriers / DPP chains / alpha work / rescales.
__global__ __launch_bounds__(256, 2) void flash_kernel(const _Float16* __restrict__ f,
                                                       const _Float16* __restrict__ g,
                                                       const _Float16* __restrict__ xT,
                                                       _Float16* __restrict__ a) {
  __shared__ _Float16 ktb[2][2][64 * 64];   // [set][tile] K, swizzled rows
  __shared__ _Float16 ptb[2][2][64 * 64];   // [buf][tile] P, swizzled rows
  __shared__ float alpha_lds[2][64];
  __shared__ float linv_lds[64];
  __shared__ int   aflag[2][4];             // per-wave "some alpha < 1" flags

  const int b   = blockIdx.x;
  const int i0  = blockIdx.y * 64;
  const int tid = threadIdx.x;
  const int wave = tid >> 6, lane = tid & 63;
  const int n16 = lane & 15, quad = lane >> 4;
  const int nlo = n16 & 7, nhi = n16 >> 3;

  // Q fragments (A-layout: m=n16, k=quad*8+j); Q pre-scaled by log2e via prep
  half8 qf[2];
  {
    const _Float16* qp = f + (size_t)(b * N_ + i0 + wave * 16 + n16) * 64 + quad * 8;
    qf[0] = *(const half8*)qp;
    qf[1] = *(const half8*)(qp + 32);
  }

  float4_t o_acc[16];   // [ti*4+ct]: rows ti*16+4q+r, cols 64w+16ct+n16
#pragma unroll
  for (int t = 0; t < 16; t++) o_acc[t] = (float4_t){0.f, 0.f, 0.f, 0.f};
  float m_i[4] = {-1e30f, -1e30f, -1e30f, -1e30f};   // log2-domain running max
  float l_i[4] = {0.f, 0.f, 0.f, 0.f};

  const _Float16* gbase = g + (size_t)(b * N_) * 64;
  const _Float16* xbase = xT + ((size_t)b * C_ + 64 * wave) * (size_t)N_;

  // K staging geometry: thread covers row krow, col blocks kcb, kcb+1
  const int krow = tid >> 2;
  const int kcb  = (tid & 3) << 1;
  const int krb  = krow & 7;

  // stage K tiles 0,1 into set 0
#pragma unroll
  for (int t = 0; t < 2; t++) {
    const _Float16* ks = gbase + (size_t)(t * 64 + krow) * 64 + (kcb << 3);
    half8 k0 = *(const half8*)ks;
    half8 k1 = *(const half8*)(ks + 8);
    _Float16* kd = ktb[0][t] + krow * 64;
    *(half8*)(kd + (((kcb    ) ^ krb) << 3)) = k0;
    *(half8*)(kd + (((kcb + 1) ^ krb) << 3)) = k1;
  }
  __syncthreads();

  for (int k = 0; k < 32; ++k) {
    const int j0A = k << 7;
    const int j0B = j0A + 64;
    const int set = k & 1;
    const int buf = k & 1;
    const int jn  = (j0A + 128) & (N_ - 1);

    // prefetch next two K tiles into regs
    half8 kpA0, kpA1, kpB0, kpB1;
    {
      const _Float16* ks = gbase + (size_t)(jn + krow) * 64 + (kcb << 3);
      kpA0 = *(const half8*)ks;
      kpA1 = *(const half8*)(ks + 8);
      ks += (size_t)64 * 64;
      kpB0 = *(const half8*)ks;
      kpB1 = *(const half8*)(ks + 8);
    }
    // V fragments for BOTH tiles, issued at iter top (latency fully hidden)
    half8 vfrA[8], vfrB[8];
#pragma unroll
    for (int s = 0; s < 2; s++)
#pragma unroll
      for (int ct = 0; ct < 4; ct++) {
        const _Float16* vp = xbase + (size_t)(16 * ct + n16) * N_ + 32 * s + 8 * quad;
        vfrA[s * 4 + ct] = *(const half8*)(vp + j0A);
        vfrB[s * 4 + ct] = *(const half8*)(vp + j0B);
      }

    // S = Q K^T for both tiles (already log2-scaled)
    float4_t sA[4], sB[4];
#pragma unroll
    for (int t = 0; t < 4; t++) {
      sA[t] = (float4_t){0.f, 0.f, 0.f, 0.f};
      sB[t] = (float4_t){0.f, 0.f, 0.f, 0.f};
    }
    {
      const _Float16* kA = ktb[set][0];
      const _Float16* kB = ktb[set][1];
      __builtin_amdgcn_s_setprio(1);
#pragma unroll
      for (int s = 0; s < 2; s++)
#pragma unroll
        for (int t = 0; t < 4; t++) {
          const int off = (16 * t + n16) * 64 + (((4 * s + quad) ^ nlo) << 3);
          sA[t] = mfma16(qf[s], *(const half8*)(kA + off), sA[t]);
          sB[t] = mfma16(qf[s], *(const half8*)(kB + off), sB[t]);
        }
      __builtin_amdgcn_s_setprio(0);
    }

    // combined online softmax over 128 j; one alpha per pair of tiles
    float alpha_r[4];
#pragma unroll
    for (int r = 0; r < 4; r++) {
      float v = fmaxf(fmaxf(fmaxf(sA[0][r], sA[1][r]), fmaxf(sA[2][r], sA[3][r])),
                      fmaxf(fmaxf(sB[0][r], sB[1][r]), fmaxf(sB[2][r], sB[3][r])));
      v = row_max16(v);
      float mn = fmaxf(m_i[r], v);
      alpha_r[r] = EXP2(m_i[r] - mn);
      m_i[r] = mn;
    }
    {
      float am = fminf(fminf(alpha_r[0], alpha_r[1]),
                       fminf(alpha_r[2], alpha_r[3]));
      unsigned long long bm = __ballot(am < 1.0f);
      if (lane == 0) aflag[buf][wave] = (bm != 0ULL) ? 1 : 0;
    }
    _Float16* pA = ptb[buf][0];
    _Float16* pB = ptb[buf][1];
#pragma unroll
    for (int r = 0; r < 4; r++) {
      float a0 = EXP2(sA[0][r] - m_i[r]);
      float a1 = EXP2(sA[1][r] - m_i[r]);
      float a2 = EXP2(sA[2][r] - m_i[r]);
      float a3 = EXP2(sA[3][r] - m_i[r]);
      float b0 = EXP2(sB[0][r] - m_i[r]);
      float b1 = EXP2(sB[1][r] - m_i[r]);
      float b2 = EXP2(sB[2][r] - m_i[r]);
      float b3 = EXP2(sB[3][r] - m_i[r]);
      float v = row_sum16((a0 + a1 + a2 + a3) + (b0 + b1 + b2 + b3));
      l_i[r] = l_i[r] * alpha_r[r] + v;
      const int row = wave * 16 + 4 * quad + r;
      const int rb  = row & 7;
      const int rbase = row * 64 + nlo;
      _Float16* prA = pA + rbase;
      prA[((nhi    ) ^ rb) << 3] = (_Float16)a0;
      prA[((nhi + 2) ^ rb) << 3] = (_Float16)a1;
      prA[((nhi + 4) ^ rb) << 3] = (_Float16)a2;
      prA[((nhi + 6) ^ rb) << 3] = (_Float16)a3;
      _Float16* prB = pB + rbase;
      prB[((nhi    ) ^ rb) << 3] = (_Float16)b0;
      prB[((nhi + 2) ^ rb) << 3] = (_Float16)b1;
      prB[((nhi + 4) ^ rb) << 3] = (_Float16)b2;
      prB[((nhi + 6) ^ rb) << 3] = (_Float16)b3;
    }
    if (n16 == 0) {
#pragma unroll
      for (int r = 0; r < 4; r++)
        alpha_lds[buf][wave * 16 + 4 * quad + r] = alpha_r[r];
    }
    // write prefetched K tiles into other set
    {
      _Float16* kd = ktb[set ^ 1][0] + krow * 64;
      *(half8*)(kd + (((kcb    ) ^ krb) << 3)) = kpA0;
      *(half8*)(kd + (((kcb + 1) ^ krb) << 3)) = kpA1;
      kd = ktb[set ^ 1][1] + krow * 64;
      *(half8*)(kd + (((kcb    ) ^ krb) << 3)) = kpB0;
      *(half8*)(kd + (((kcb + 1) ^ krb) << 3)) = kpB1;
    }
    __syncthreads();

    // rescale O once per 128 j, skipped when no row max moved (alpha==1)
#pragma unroll
    for (int ti = 0; ti < 4; ti++) {
      if (aflag[buf][ti]) {
#pragma unroll
        for (int r = 0; r < 4; r++) {
          float al = alpha_lds[buf][ti * 16 + 4 * quad + r];
#pragma unroll
          for (int ct = 0; ct < 4; ct++) o_acc[ti * 4 + ct][r] *= al;
        }
      }
    }

    // O += P_A V_A + P_B V_B
    __builtin_amdgcn_s_setprio(1);
#pragma unroll
    for (int s = 0; s < 2; s++)
#pragma unroll
      for (int ti = 0; ti < 4; ti++) {
        const int off = (16 * ti + n16) * 64 + (((4 * s + quad) ^ nlo) << 3);
        half8 afA = *(const half8*)(pA + off);
        half8 afB = *(const half8*)(pB + off);
#pragma unroll
        for (int ct = 0; ct < 4; ct++) {
          o_acc[ti * 4 + ct] = mfma16(afA, vfrA[s * 4 + ct], o_acc[ti * 4 + ct]);
          o_acc[ti * 4 + ct] = mfma16(afB, vfrB[s * 4 + ct], o_acc[ti * 4 + ct]);
        }
      }
    __builtin_amdgcn_s_setprio(0);
  }

  // share 1/l across waves, then write out a = O / l
  if (n16 == 0) {
#pragma unroll
    for (int r = 0; r < 4; r++)
      linv_lds[wave * 16 + 4 * quad + r] = 1.f / l_i[r];
  }
  __syncthreads();
#pragma unroll
  for (int ti = 0; ti < 4; ti++)
#pragma unroll
    for (int r = 0; r < 4; r++) {
      float il = linv_lds[ti * 16 + 4 * quad + r];
      size_t orow = (size_t)(b * N_ + i0 + ti * 16 + 4 * quad + r) * C_;
#pragma unroll
      for (int ct = 0; ct < 4; ct++)
        a[orow + 64 * wave + 16 * ct + n16] =
            (_Float16)(o_acc[ti * 4 + ct][r] * il);
    }
}

// ---------------- epilogue GEMM: out = gamma * (a @ Whv) + x ---------------------
__global__ __launch_bounds__(256) void out_kernel(const _Float16* __restrict__ a,
                                                  const _Float16* __restrict__ whvt,
                                                  const float* __restrict__ x,
                                                  const float* __restrict__ gamma,
                                                  float* __restrict__ out) {
  int tid  = threadIdx.x;
  int wave = tid >> 6, lane = tid & 63;
  int n16  = lane & 15, quad = lane >> 4;
  int row  = blockIdx.x * 64 + wave * 16 + n16;
  float4_t acc[16];
#pragma unroll
  for (int t = 0; t < 16; t++) acc[t] = (float4_t){0.f, 0.f, 0.f, 0.f};
  for (int k0 = 0; k0 < 256; k0 += 32) {
    half8 af = *(const half8*)(a + (size_t)row * C_ + k0 + quad * 8);
#pragma unroll
    for (int t = 0; t < 16; t++) {
      half8 bf = *(const half8*)(whvt + (size_t)(t * 16 + n16) * 256 + k0 + quad * 8);
      acc[t] = mfma16(af, bf, acc[t]);
    }
  }
  float gm = gamma[0];
  int orow = blockIdx.x * 64 + wave * 16 + quad * 4;
#pragma unroll
  for (int t = 0; t < 16; t++) {
#pragma unroll
    for (int r = 0; r < 4; r++) {
      size_t idx = (size_t)(orow + r) * C_ + t * 16 + n16;
      out[idx] = gm * acc[t][r] + x[idx];
    }
  }
}

extern "C" void kernel_launch(void* const* d_in, const int* in_sizes, int n_in,
                              void* d_out, int out_size, void* d_ws, size_t ws_size,
                              hipStream_t stream) {
  const float* x     = (const float*)d_in[0];
  const float* Wf    = (const float*)d_in[1];
  const float* Wg    = (const float*)d_in[2];
  const float* Wh    = (const float*)d_in[3];
  const float* Wv    = (const float*)d_in[4];
  const float* gamma = (const float*)d_in[5];
  float* out = (float*)d_out;

  char* w = (char*)d_ws;
  _Float16* whvt = (_Float16*)(w);                                  // 128 KiB
  _Float16* wfgt = (_Float16*)(w + 131072);                         //  64 KiB
  _Float16* fb   = (_Float16*)(w + 196608);                         //   4 MiB
  _Float16* gb   = (_Float16*)(w + 196608 + 4194304);               //   4 MiB
  _Float16* xT   = (_Float16*)(w + 196608 + 2 * 4194304);           //  16 MiB
  _Float16* ab   = (_Float16*)(w + 196608 + 2 * 4194304 + 16777216);//  16 MiB

  hipLaunchKernelGGL(prep_whvt,  dim3(256),     dim3(256), 0, stream, Wh, Wv, whvt);
  hipLaunchKernelGGL(prep_wfgt,  dim3(128),     dim3(256), 0, stream, Wf, Wg, wfgt);
  hipLaunchKernelGGL(transpose_x,dim3(1024, 8), dim3(256), 0, stream, x, xT);
  hipLaunchKernelGGL(fg_kernel,  dim3(512),     dim3(256), 0, stream, x, wfgt, fb, gb);
  hipLaunchKernelGGL(flash_kernel, dim3(8, 64), dim3(256), 0, stream, fb, gb, xT, ab);
  hipLaunchKernelGGL(out_kernel, dim3(512),     dim3(256), 0, stream, ab, whvt, x, gamma, out);
}

// Round 6
// 286.230 us; speedup vs baseline: 1.1828x; 1.0538x over previous
//
#include <hip/hip_runtime.h>

typedef _Float16 half8   __attribute__((ext_vector_type(8)));
typedef _Float16 half4_t __attribute__((ext_vector_type(4)));
typedef float    float4_t __attribute__((ext_vector_type(4)));

#define B_   8
#define N_   4096
#define C_   256
#define F_   64

#if defined(__has_builtin) && __has_builtin(__builtin_amdgcn_exp2f)
#define EXP2(x) __builtin_amdgcn_exp2f(x)
#else
#define EXP2(x) exp2f(x)
#endif
#define LOG2E 1.44269504f

static __device__ __forceinline__ float4_t mfma16(half8 a, half8 b, float4_t c) {
  return __builtin_amdgcn_mfma_f32_16x16x32_f16(a, b, c, 0, 0, 0);
}

// DPP cross-lane within 16-lane rows: row_ror:N = 0x120|N.
template <int CTRL>
static __device__ __forceinline__ float dpp_f(float x) {
  return __int_as_float(__builtin_amdgcn_update_dpp(
      __float_as_int(x), __float_as_int(x), CTRL, 0xF, 0xF, false));
}
static __device__ __forceinline__ float row_max16(float v) {
  v = fmaxf(v, dpp_f<0x128>(v));
  v = fmaxf(v, dpp_f<0x124>(v));
  v = fmaxf(v, dpp_f<0x122>(v));
  v = fmaxf(v, dpp_f<0x121>(v));
  return v;
}
static __device__ __forceinline__ float row_sum16(float v) {
  v += dpp_f<0x128>(v);
  v += dpp_f<0x124>(v);
  v += dpp_f<0x122>(v);
  v += dpp_f<0x121>(v);
  return v;
}

// ------------- fused prep: whvt (blocks 0..255) + wfgt (blocks 256..383) ---------
// whvt[d][c] = sum_e Wh[c][e]*Wv[e][d]; wfgt[n][c] = (n<64?Wf[c][n]*log2e:Wg[c][n-64])
__global__ __launch_bounds__(256) void prep_kernel(const float* __restrict__ Wh,
                                                   const float* __restrict__ Wv,
                                                   const float* __restrict__ Wf,
                                                   const float* __restrict__ Wg,
                                                   _Float16* __restrict__ whvt,
                                                   _Float16* __restrict__ wfgt) {
  int c = threadIdx.x;
  if (blockIdx.x < 256) {
    int d = blockIdx.x;    // uniform per block -> Wv reads become s_loads
    const float4_t* whr = (const float4_t*)(Wh + (size_t)c * 256);
    float acc = 0.f;
#pragma unroll 8
    for (int e4 = 0; e4 < 64; ++e4) {
      float4_t w4 = whr[e4];
      acc += w4[0] * Wv[(e4 * 4 + 0) * 256 + d];
      acc += w4[1] * Wv[(e4 * 4 + 1) * 256 + d];
      acc += w4[2] * Wv[(e4 * 4 + 2) * 256 + d];
      acc += w4[3] * Wv[(e4 * 4 + 3) * 256 + d];
    }
    whvt[d * 256 + c] = (_Float16)acc;
  } else {
    int n = blockIdx.x - 256;   // 0..127
    float v = (n < 64) ? Wf[c * 64 + n] * LOG2E : Wg[c * 64 + (n - 64)];
    wfgt[n * 256 + c] = (_Float16)v;
  }
}

// ------- fused f,g GEMM + x transpose: reads x ONCE from HBM ---------------------
// Phase A: [32768x256] @ wfgt^T -> f16 f,g [32768x64] (verbatim fg_kernel).
// Phase B: xT[b][c][n] = (f16)x[b][n][c] for this block's 64 rows, using the
// proven 32x32 LDS-transpose (x re-reads hit L1/L2: the tile was just loaded).
__global__ __launch_bounds__(256) void fgt_kernel(const float* __restrict__ x,
                                                  const _Float16* __restrict__ wfgt,
                                                  _Float16* __restrict__ f,
                                                  _Float16* __restrict__ g,
                                                  _Float16* __restrict__ xT) {
  __shared__ float tile[32][33];
  int tid  = threadIdx.x;
  int wave = tid >> 6, lane = tid & 63;
  int n16  = lane & 15, quad = lane >> 4;
  int row  = blockIdx.x * 64 + wave * 16 + n16;   // A m-index (global row)
  float4_t acc[8];
#pragma unroll
  for (int t = 0; t < 8; t++) acc[t] = (float4_t){0.f, 0.f, 0.f, 0.f};
  for (int k0 = 0; k0 < 256; k0 += 32) {
    const float* xp = x + (size_t)row * C_ + k0 + quad * 8;
    float4_t x0 = *(const float4_t*)xp;
    float4_t x1 = *(const float4_t*)(xp + 4);
    half8 af;
#pragma unroll
    for (int j = 0; j < 4; j++) { af[j] = (_Float16)x0[j]; af[4 + j] = (_Float16)x1[j]; }
#pragma unroll
    for (int t = 0; t < 8; t++) {
      half8 bf = *(const half8*)(wfgt + (size_t)(t * 16 + n16) * 256 + k0 + quad * 8);
      acc[t] = mfma16(af, bf, acc[t]);
    }
  }
  int orow = blockIdx.x * 64 + wave * 16 + quad * 4;  // D row = quad*4+reg
#pragma unroll
  for (int t = 0; t < 8; t++) {
#pragma unroll
    for (int r = 0; r < 4; r++) {
      _Float16 v = (_Float16)acc[t][r];
      int col = t * 16 + n16;
      if (t < 4) f[(size_t)(orow + r) * 64 + col] = v;
      else       g[(size_t)(orow + r) * 64 + col - 64] = v;
    }
  }

  // ---- Phase B: transpose this block's 64 rows x 256 cols into xT -------------
  const int b   = blockIdx.x >> 6;
  const int nb  = (blockIdx.x & 63) << 6;           // n-tile base (64 rows)
  const int tr  = tid >> 3;                          // 0..31
  const int tc  = (tid & 7) << 2;                    // 0,4,..,28
#pragma unroll 1
  for (int s = 0; s < 16; ++s) {
    const int n0 = nb + ((s & 1) << 5);              // n sub-block (32)
    const int c0 = (s >> 1) << 5;                    // c sub-block (32)
    __syncthreads();                                 // protect tile reuse
    const float* src = x + ((size_t)(b * N_ + n0 + tr)) * C_ + c0 + tc;
    float4_t v = *(const float4_t*)src;
    tile[tr][tc + 0] = v[0]; tile[tr][tc + 1] = v[1];
    tile[tr][tc + 2] = v[2]; tile[tr][tc + 3] = v[3];
    __syncthreads();
    half4_t o;
    o[0] = (_Float16)tile[tc + 0][tr];
    o[1] = (_Float16)tile[tc + 1][tr];
    o[2] = (_Float16)tile[tc + 2][tr];
    o[3] = (_Float16)tile[tc + 3][tr];
    _Float16* dst = xT + ((size_t)(b * C_ + c0 + tr)) * N_ + n0 + tc;
    *(half4_t*)dst = o;
  }
}

// ---------------- flash attention (C-split): a = softmax(f g^T) @ x --------------
// Known-good R1 structure (151 us): KVBLK=64, no KV split, register K-prefetch,
// all V loads at iter top, (256,2) -> ~160 unified regs, 2 blocks/CU, no spill.
// Q is pre-scaled by log2e in prep, so softmax runs in base-2 directly.
__global__ __launch_bounds__(256, 2) void flash_kernel(const _Float16* __restrict__ f,
                                                       const _Float16* __restrict__ g,
                                                       const _Float16* __restrict__ xT,
                                                       _Float16* __restrict__ a) {
  __shared__ _Float16 ktb2[2][64 * 64];   // K tile, swizzled
  __shared__ _Float16 ptb2[2][64 * 64];   // P tile, swizzled
  __shared__ float alpha_lds[2][64];
  __shared__ float linv_lds[64];

  const int b   = blockIdx.x;
  const int i0  = blockIdx.y * 64;
  const int tid = threadIdx.x;
  const int wave = tid >> 6, lane = tid & 63;
  const int n16 = lane & 15, quad = lane >> 4;
  const int nlo = n16 & 7, nhi = n16 >> 3;

  // Q fragments (A-layout: m=n16, k=quad*8+j), rows 16w..16w+15 of this i-tile
  half8 qf[2];
  {
    const _Float16* qp = f + (size_t)(b * N_ + i0 + wave * 16 + n16) * 64 + quad * 8;
    qf[0] = *(const half8*)qp;
    qf[1] = *(const half8*)(qp + 32);
  }

  float4_t o_acc[16];   // [ti*4+ct]: rows ti*16+4q+r, cols 64w+16ct+n16
#pragma unroll
  for (int t = 0; t < 16; t++) o_acc[t] = (float4_t){0.f, 0.f, 0.f, 0.f};
  float m_i[4] = {-1e30f, -1e30f, -1e30f, -1e30f};   // log2-domain running max
  float l_i[4] = {0.f, 0.f, 0.f, 0.f};

  const _Float16* gbase = g + (size_t)(b * N_) * 64;
  const _Float16* xbase = xT + ((size_t)b * C_ + 64 * wave) * (size_t)N_;

  // K staging geometry: thread covers row krow, col blocks kcb, kcb+1
  const int krow = tid >> 2;
  const int kcb  = (tid & 3) << 1;
  const int krb  = krow & 7;

  // stage K tile for j0=0
  {
    const _Float16* ks = gbase + (size_t)krow * 64 + (kcb << 3);
    half8 k0 = *(const half8*)ks;
    half8 k1 = *(const half8*)(ks + 8);
    _Float16* kd = ktb2[0] + krow * 64;
    *(half8*)(kd + (((kcb    ) ^ krb) << 3)) = k0;
    *(half8*)(kd + (((kcb + 1) ^ krb) << 3)) = k1;
  }
  __syncthreads();

  for (int k = 0; k < 64; ++k) {
    const int j0  = k << 6;
    const int buf = k & 1;
    const int j0n = (j0 + 64) & (N_ - 1);

    // prefetch next K tile into regs
    half8 kp0, kp1;
    {
      const _Float16* ks = gbase + (size_t)(j0n + krow) * 64 + (kcb << 3);
      kp0 = *(const half8*)ks;
      kp1 = *(const half8*)(ks + 8);
    }
    // V fragments for this iter straight from global (L2)
    half8 vfr[8];
#pragma unroll
    for (int s = 0; s < 2; s++)
#pragma unroll
      for (int ct = 0; ct < 4; ct++)
        vfr[s * 4 + ct] = *(const half8*)(xbase + (size_t)(16 * ct + n16) * N_ +
                                          j0 + 32 * s + 8 * quad);

    // S = Q K^T for this wave's 16 rows (log2-scaled via prep)
    float4_t s_acc[4];
#pragma unroll
    for (int t = 0; t < 4; t++) s_acc[t] = (float4_t){0.f, 0.f, 0.f, 0.f};
    {
      const _Float16* ktb = ktb2[buf];
      __builtin_amdgcn_s_setprio(1);
#pragma unroll
      for (int s = 0; s < 2; s++)
#pragma unroll
        for (int t = 0; t < 4; t++) {
          half8 bf = *(const half8*)(ktb + (16 * t + n16) * 64 +
                                     (((4 * s + quad) ^ nlo) << 3));
          s_acc[t] = mfma16(qf[s], bf, s_acc[t]);
        }
      __builtin_amdgcn_s_setprio(0);
    }

    // online softmax (base-2) for this wave's rows; write P (swizzled) + alpha
    float alpha_r[4];
#pragma unroll
    for (int r = 0; r < 4; r++) {
      float v = fmaxf(fmaxf(s_acc[0][r], s_acc[1][r]),
                      fmaxf(s_acc[2][r], s_acc[3][r]));
      v = row_max16(v);                      // DPP reduce, no LDS traffic
      float mn = fmaxf(m_i[r], v);
      alpha_r[r] = EXP2(m_i[r] - mn);
      m_i[r] = mn;
    }
    _Float16* pb = ptb2[buf];
#pragma unroll
    for (int r = 0; r < 4; r++) {
      float s0 = EXP2(s_acc[0][r] - m_i[r]);
      float s1 = EXP2(s_acc[1][r] - m_i[r]);
      float s2 = EXP2(s_acc[2][r] - m_i[r]);
      float s3 = EXP2(s_acc[3][r] - m_i[r]);
      float v = row_sum16(s0 + s1 + s2 + s3); // DPP reduce
      l_i[r] = l_i[r] * alpha_r[r] + v;
      const int row = wave * 16 + 4 * quad + r;
      const int rb  = row & 7;
      _Float16* pr = pb + row * 64 + nlo;
      pr[((nhi    ) ^ rb) << 3] = (_Float16)s0;
      pr[((nhi + 2) ^ rb) << 3] = (_Float16)s1;
      pr[((nhi + 4) ^ rb) << 3] = (_Float16)s2;
      pr[((nhi + 6) ^ rb) << 3] = (_Float16)s3;
    }
    if (n16 == 0) {
#pragma unroll
      for (int r = 0; r < 4; r++)
        alpha_lds[buf][wave * 16 + 4 * quad + r] = alpha_r[r];
    }
    // write prefetched K tile into other buffer
    {
      _Float16* kd = ktb2[buf ^ 1] + krow * 64;
      *(half8*)(kd + (((kcb    ) ^ krb) << 3)) = kp0;
      *(half8*)(kd + (((kcb + 1) ^ krb) << 3)) = kp1;
    }
    __syncthreads();

    // rescale O by alpha of each row (broadcast LDS reads)
#pragma unroll
    for (int ti = 0; ti < 4; ti++)
#pragma unroll
      for (int r = 0; r < 4; r++) {
        float al = alpha_lds[buf][ti * 16 + 4 * quad + r];
#pragma unroll
        for (int ct = 0; ct < 4; ct++) o_acc[ti * 4 + ct][r] *= al;
      }

    // O += P V  (P from shared LDS, V from regs)
    __builtin_amdgcn_s_setprio(1);
#pragma unroll
    for (int s = 0; s < 2; s++)
#pragma unroll
      for (int ti = 0; ti < 4; ti++) {
        half8 af = *(const half8*)(pb + (16 * ti + n16) * 64 +
                                   (((4 * s + quad) ^ nlo) << 3));
#pragma unroll
        for (int ct = 0; ct < 4; ct++)
          o_acc[ti * 4 + ct] = mfma16(af, vfr[s * 4 + ct], o_acc[ti * 4 + ct]);
      }
    __builtin_amdgcn_s_setprio(0);
  }

  // share 1/l across waves, then write out a = O / l
  if (n16 == 0) {
#pragma unroll
    for (int r = 0; r < 4; r++)
      linv_lds[wave * 16 + 4 * quad + r] = 1.f / l_i[r];
  }
  __syncthreads();
#pragma unroll
  for (int ti = 0; ti < 4; ti++)
#pragma unroll
    for (int r = 0; r < 4; r++) {
      float il = linv_lds[ti * 16 + 4 * quad + r];
      size_t orow = (size_t)(b * N_ + i0 + ti * 16 + 4 * quad + r) * C_;
#pragma unroll
      for (int ct = 0; ct < 4; ct++)
        a[orow + 64 * wave + 16 * ct + n16] =
            (_Float16)(o_acc[ti * 4 + ct][r] * il);
    }
}

// ---------------- epilogue GEMM: out = gamma * (a @ Whv) + x ---------------------
__global__ __launch_bounds__(256) void out_kernel(const _Float16* __restrict__ a,
                                                  const _Float16* __restrict__ whvt,
                                                  const float* __restrict__ x,
                                                  const float* __restrict__ gamma,
                                                  float* __restrict__ out) {
  int tid  = threadIdx.x;
  int wave = tid >> 6, lane = tid & 63;
  int n16  = lane & 15, quad = lane >> 4;
  int row  = blockIdx.x * 64 + wave * 16 + n16;
  float4_t acc[16];
#pragma unroll
  for (int t = 0; t < 16; t++) acc[t] = (float4_t){0.f, 0.f, 0.f, 0.f};
  for (int k0 = 0; k0 < 256; k0 += 32) {
    half8 af = *(const half8*)(a + (size_t)row * C_ + k0 + quad * 8);
#pragma unroll
    for (int t = 0; t < 16; t++) {
      half8 bf = *(const half8*)(whvt + (size_t)(t * 16 + n16) * 256 + k0 + quad * 8);
      acc[t] = mfma16(af, bf, acc[t]);
    }
  }
  float gm = gamma[0];
  int orow = blockIdx.x * 64 + wave * 16 + quad * 4;
#pragma unroll
  for (int t = 0; t < 16; t++) {
#pragma unroll
    for (int r = 0; r < 4; r++) {
      size_t idx = (size_t)(orow + r) * C_ + t * 16 + n16;
      out[idx] = gm * acc[t][r] + x[idx];
    }
  }
}

extern "C" void kernel_launch(void* const* d_in, const int* in_sizes, int n_in,
                              void* d_out, int out_size, void* d_ws, size_t ws_size,
                              hipStream_t stream) {
  const float* x     = (const float*)d_in[0];
  const float* Wf    = (const float*)d_in[1];
  const float* Wg    = (const float*)d_in[2];
  const float* Wh    = (const float*)d_in[3];
  const float* Wv    = (const float*)d_in[4];
  const float* gamma = (const float*)d_in[5];
  float* out = (float*)d_out;

  char* w = (char*)d_ws;
  _Float16* whvt = (_Float16*)(w);                                  // 128 KiB
  _Float16* wfgt = (_Float16*)(w + 131072);                         //  64 KiB
  _Float16* fb   = (_Float16*)(w + 196608);                         //   4 MiB
  _Float16* gb   = (_Float16*)(w + 196608 + 4194304);               //   4 MiB
  _Float16* xT   = (_Float16*)(w + 196608 + 2 * 4194304);           //  16 MiB
  _Float16* ab   = (_Float16*)(w + 196608 + 2 * 4194304 + 16777216);//  16 MiB

  hipLaunchKernelGGL(prep_kernel, dim3(384),   dim3(256), 0, stream,
                     Wh, Wv, Wf, Wg, whvt, wfgt);
  hipLaunchKernelGGL(fgt_kernel,  dim3(512),   dim3(256), 0, stream,
                     x, wfgt, fb, gb, xT);
  hipLaunchKernelGGL(flash_kernel, dim3(8, 64), dim3(256), 0, stream, fb, gb, xT, ab);
  hipLaunchKernelGGL(out_kernel,  dim3(512),   dim3(256), 0, stream, ab, whvt, x, gamma, out);
}